// Round 11
// baseline (276.045 us; speedup 1.0000x reference)
//
#include <hip/hip_runtime.h>
#include <hip/hip_bf16.h>

// Problem constants (MambaBlock): B=2, L=2048, d_model=1024, d_inner=2048,
// d_conv=4, dt_rank=64, d_state=16. All inputs/output float32 (per reference).

#define BATCH   2
#define SEQLEN  2048
#define DMODEL  1024
#define DINNER  2048
#define DCONV   4
#define DTRANK  64
#define DSTATE  16
#define BL      (BATCH * SEQLEN)         // 4096
#define NXZ     (2 * DINNER)             // 4096
#define XDBL_N  (DTRANK + 2 * DSTATE)    // 96
#define LCH     32                       // chunk length for parallel scan
#define NCHUNK  (SEQLEN / LCH)           // 64 chunks per sequence
#define KSPLIT  8                        // channel split for conv/x_dbl blocks
#define KC      (DINNER / KSPLIT)        // 256
#define KS_OUT  4                        // split-K for the out GEMM
#define KCO     (DINNER / KS_OUT)        // 512
#define XDP     128                      // padded partial width for x_dbl
#define ALDS    264                      // padded LDS row stride (bf16, 16B-aligned rows)

typedef __bf16 bf16x8 __attribute__((ext_vector_type(8)));
typedef __bf16 bf16x4 __attribute__((ext_vector_type(4)));
typedef float  floatx4 __attribute__((ext_vector_type(4)));

__device__ __forceinline__ float silu_f(float v) {
    return v / (1.f + __expf(-v));
}

// Fast softplus via native v_exp_f32/v_log_f32 (error ~1e-7, << bf16 noise).
__device__ __forceinline__ float softplus_f(float v) {
    return (v > 20.f) ? v : __logf(1.f + __expf(v));
}

// Native base-2 exp (v_exp_f32). __exp2f collides with a glibc macro.
__device__ __forceinline__ float fast_exp2(float v) {
    return __builtin_amdgcn_exp2f(v);
}

__device__ __forceinline__ void gload_lds16(const __bf16* g, __bf16* l) {
    __builtin_amdgcn_global_load_lds(
        (const __attribute__((address_space(1))) void*)g,
        (__attribute__((address_space(3))) void*)l, 16, 0, 0);
}

// counted vmcnt wait; "memory" clobber pins C++ LDS reads on the correct side
#define VMW(n) asm volatile("s_waitcnt vmcnt(" #n ")" ::: "memory")
#define BARX() __builtin_amdgcn_s_barrier()

// ---------------------------------------------------------------------------
// 256x256 8-phase bf16 GEMM (T1+T2+T3+T4+T5 template, plain HIP).
//   BM=BN=256, BK=64, 512 threads = 8 waves (2M x 4N), 128x64 out per wave.
//   LDS 128 KiB: 2 dbuf x { A: 2 half-slots 128x64, B: 2 half-slots 128x64 }.
//   K is the LOOP length (must be even multiple of 64, >= 256); lda is the
//   K-dim stride of both A and BT. blockIdx.y selects a K-split chunk
//   (kbase = blockIdx.y * K); fp32 stores go to partial blockIdx.y * M * N.
//   Waits: vmcnt(8) end of ph1/ph5, vmcnt(6) end of ph3/ph7 (never 0 in
//   the main loop); every LDS overwrite is >=1 barrier after its last read.
//   Epilogues: smem (dead after K-loop) reused as a C-tile staging buffer
//   (XOR-swizzled 16B chunks) -> coalesced stores. bf16: full tile, bf16x8
//   row stores. fp32: two 128-row passes, float4 row stores (1KB/wave-instr).
// EPI: 0 = fp32 store; 1 = softplus fp32; 2 = bf16 store; 3 = softplus bf16.
// ---------------------------------------------------------------------------
template <int BUF, int QA>
__device__ __forceinline__ void rdA(const char* rA, bf16x8 (&aF)[4][2]) {
#pragma unroll
    for (int j = 0; j < 4; ++j) {
        aF[j][0] = *(const bf16x8*)(rA + BUF * 65536 + ((QA * 4 + j) * 2 + 0) * 1024);
        aF[j][1] = *(const bf16x8*)(rA + BUF * 65536 + ((QA * 4 + j) * 2 + 1) * 1024);
    }
}

template <int BUF, int QB>
__device__ __forceinline__ void rdB(const char* rB, bf16x8 (&bF)[2][2]) {
#pragma unroll
    for (int f = 0; f < 2; ++f) {
        bF[f][0] = *(const bf16x8*)(rB + BUF * 65536 + QB * 8192 + f * 2048 + 0);
        bF[f][1] = *(const bf16x8*)(rB + BUF * 65536 + QB * 8192 + f * 2048 + 1024);
    }
}

template <int QA, int QB>
__device__ __forceinline__ void mf16(const bf16x8 (&aF)[4][2], const bf16x8 (&bF)[2][2],
                                     floatx4 (&acc)[8][4]) {
    __builtin_amdgcn_s_setprio(1);
#pragma unroll
    for (int ks = 0; ks < 2; ++ks)
#pragma unroll
        for (int j = 0; j < 4; ++j)
#pragma unroll
            for (int f = 0; f < 2; ++f)
                acc[QA * 4 + j][QB * 2 + f] = __builtin_amdgcn_mfma_f32_16x16x32_bf16(
                    aF[j][ks], bF[f][ks], acc[QA * 4 + j][QB * 2 + f], 0, 0, 0);
    __builtin_amdgcn_s_setprio(0);
}

template <int BUF, int QA>
__device__ __forceinline__ void stA2(const __bf16* gAs, char* sm, int lda, int w, int t) {
    gload_lds16(gAs + (size_t)(QA * 64) * lda + t * 64,
                (__bf16*)(sm + BUF * 65536 + QA * 8192 + w * 1024));
    gload_lds16(gAs + (size_t)(128 + QA * 64) * lda + t * 64,
                (__bf16*)(sm + BUF * 65536 + 16384 + QA * 8192 + w * 1024));
}

template <int BUF, int QB>
__device__ __forceinline__ void stB2(const __bf16* gBs, char* sm, int lda, int w, int t) {
    gload_lds16(gBs + (size_t)(QB * 32) * lda + t * 64,
                (__bf16*)(sm + BUF * 65536 + 32768 + QB * 8192 + w * 1024));
    gload_lds16(gBs + (size_t)(128 + QB * 32) * lda + t * 64,
                (__bf16*)(sm + BUF * 65536 + 32768 + 16384 + QB * 8192 + w * 1024));
}

template <int EPI>
__global__ __launch_bounds__(512, 2) void gemm_bt_256(
    const __bf16* __restrict__ A,
    const __bf16* __restrict__ BT,
    void* __restrict__ Cv,
    int M, int N, int K, int lda,
    const float* __restrict__ bias)
{
    __shared__ __align__(16) char smem[131072];

    const int tid  = threadIdx.x;
    const int w    = tid >> 6;
    const int lane = tid & 63;

    // XCD-aware bijective block swizzle (gridDim.x % 8 == 0).
    const int cpx = gridDim.x >> 3;
    const int swz = (blockIdx.x & 7) * cpx + (blockIdx.x >> 3);
    const int ntn = N >> 8;
    const int row0 = (swz / ntn) << 8;
    const int col0 = (swz % ntn) << 8;
    const int kbase = blockIdx.y * K;          // K-split chunk base

    // ---- stage-side decode (thread-constant): physical granule P=tid maps to
    // logical (row, col) so global src is pre-inverse-swizzled; LDS dest linear.
    const int P     = tid;
    const int rr    = (P >> 2) & 15;
    const int qq    = (P & 3) ^ (2 * ((P >> 5) & 1));
    const int colE  = (((P >> 6) & 1) * 4 + qq) * 8;
    const int rgP   = P >> 7;                              // 0..3
    const int rowAu = rgP * 16 + rr;                       // within 64-row qa unit
    const int rowBu = (rgP >> 1) * 64 + (rgP & 1) * 16 + rr; // within slot (+qb*32 at use)

    const __bf16* gAs = A  + (size_t)(row0 + rowAu) * lda + kbase + colE;
    const __bf16* gBs = BT + (size_t)(col0 + rowBu) * lda + kbase + colE;
    char* sm = smem;

    // ---- read-side swizzled lane offset (matches stage decode; involution)
    const int lsw = ((lane & 15) * 4 + ((lane >> 4) ^ (2 * ((lane >> 3) & 1)))) * 16;
    const char* rA = smem + (w >> 2) * 16384 + lsw;
    const char* rB = smem + 32768 + ((w & 3) >> 1) * 16384 + ((w & 3) & 1) * 4096 + lsw;

    floatx4 acc[8][4];
#pragma unroll
    for (int i = 0; i < 8; ++i)
#pragma unroll
        for (int j = 0; j < 4; ++j)
            acc[i][j] = (floatx4){0.f, 0.f, 0.f, 0.f};
    bf16x8 aF[4][2], bF[2][2];

    const int NT = K >> 6;       // 64-wide K tiles (even, >= 4)
    const int NI = NT >> 1;

    // ---- prologue: 12 loads; vmcnt(6) leaves {Aqa1(t0), Aqa0(t1), Bqb1(t1)}
    stA2<0, 0>(gAs, sm, lda, w, 0);
    stB2<0, 0>(gBs, sm, lda, w, 0);
    stB2<0, 1>(gBs, sm, lda, w, 0);
    stA2<0, 1>(gAs, sm, lda, w, 0);
    stA2<1, 0>(gAs, sm, lda, w, 1);
    stB2<1, 1>(gBs, sm, lda, w, 1);
    VMW(6);
    BARX();

    for (int i = 0; i < NI - 1; ++i) {
        const int t1 = 2 * i + 1, t2 = 2 * i + 2, t3 = 2 * i + 3;
        // ph0: tile 2i (buf0), q=(0,0)
        rdA<0, 0>(rA, aF); rdB<0, 0>(rB, bF);
        stB2<1, 0>(gBs, sm, lda, w, t1);
        BARX(); mf16<0, 0>(aF, bF, acc); BARX();
        // ph1: (0,1)
        rdB<0, 1>(rB, bF);
        stA2<1, 1>(gAs, sm, lda, w, t1);
        BARX(); mf16<0, 1>(aF, bF, acc); VMW(8); BARX();
        // ph2: (1,1)
        rdA<0, 1>(rA, aF);
        stA2<0, 0>(gAs, sm, lda, w, t2);
        BARX(); mf16<1, 1>(aF, bF, acc); BARX();
        // ph3: (1,0)  (re-read B qb0)
        rdB<0, 0>(rB, bF);
        stB2<0, 1>(gBs, sm, lda, w, t2);
        BARX(); mf16<1, 0>(aF, bF, acc); VMW(6); BARX();
        // ph4: tile 2i+1 (buf1), q=(0,0)
        rdA<1, 0>(rA, aF); rdB<1, 0>(rB, bF);
        stB2<0, 0>(gBs, sm, lda, w, t2);
        BARX(); mf16<0, 0>(aF, bF, acc); BARX();
        // ph5: (0,1)
        rdB<1, 1>(rB, bF);
        stA2<0, 1>(gAs, sm, lda, w, t2);
        BARX(); mf16<0, 1>(aF, bF, acc); VMW(8); BARX();
        // ph6: (1,1)
        rdA<1, 1>(rA, aF);
        stA2<1, 0>(gAs, sm, lda, w, t3);
        BARX(); mf16<1, 1>(aF, bF, acc); BARX();
        // ph7: (1,0)
        rdB<1, 0>(rB, bF);
        stB2<1, 1>(gBs, sm, lda, w, t3);
        BARX(); mf16<1, 0>(aF, bF, acc); VMW(6); BARX();
    }
    // ---- tail iteration (tiles NT-2, NT-1): no further stages; drain 2 -> 0
    {
        const int t1 = NT - 1;
        rdA<0, 0>(rA, aF); rdB<0, 0>(rB, bF);
        stB2<1, 0>(gBs, sm, lda, w, t1);
        BARX(); mf16<0, 0>(aF, bF, acc); BARX();
        rdB<0, 1>(rB, bF);
        stA2<1, 1>(gAs, sm, lda, w, t1);
        BARX(); mf16<0, 1>(aF, bF, acc); VMW(8); BARX();
        rdA<0, 1>(rA, aF);
        BARX(); mf16<1, 1>(aF, bF, acc); BARX();
        rdB<0, 0>(rB, bF);
        BARX(); mf16<1, 0>(aF, bF, acc); VMW(2); BARX();
        rdA<1, 0>(rA, aF); rdB<1, 0>(rB, bF);
        BARX(); mf16<0, 0>(aF, bF, acc); BARX();
        rdB<1, 1>(rB, bF);
        BARX(); mf16<0, 1>(aF, bF, acc); VMW(0); BARX();
        rdA<1, 1>(rA, aF);
        BARX(); mf16<1, 1>(aF, bF, acc); BARX();
        rdB<1, 0>(rB, bF);
        BARX(); mf16<1, 0>(aF, bF, acc);
    }

    // ---- epilogue: acc fragment layout col=lane&15, row=(lane>>4)*4+reg
    const int lrow = lane & 15, quad = lane >> 4;

    if (EPI == 2 || EPI == 3) {
        // bf16 path: stage full 256x256 bf16 tile through smem (131072 B,
        // XOR-swizzled 16B chunks) -> coalesced bf16x8 row stores.
        __syncthreads();   // all waves done with K-loop LDS reads
#pragma unroll
        for (int fi = 0; fi < 8; ++fi) {
#pragma unroll
            for (int cf = 0; cf < 4; ++cf) {
                const int lc = (w & 3) * 64 + cf * 16 + lrow;       // 0..255
                const float bv = (EPI == 3) ? bias[col0 + lc] : 0.f;
#pragma unroll
                for (int r = 0; r < 4; ++r) {
                    const int lr = (w >> 2) * 128 + fi * 16 + quad * 4 + r;  // 0..255
                    float v = acc[fi][cf][r];
                    if (EPI == 3) v = softplus_f(v + bv);
                    const int ck = (lc >> 3) ^ ((lr >> 2) & 7);
                    *(__bf16*)(smem + lr * 512 + ck * 16 + (lc & 7) * 2) = (__bf16)v;
                }
            }
        }
        __syncthreads();
#pragma unroll
        for (int it = 0; it < 16; ++it) {
            const int row = it * 16 + w * 2 + (lane >> 5);          // 0..255
            const int cr  = lane & 31;
            const int ck  = cr ^ ((row >> 2) & 7);
            bf16x8 v = *(const bf16x8*)(smem + row * 512 + ck * 16);
            *(bf16x8*)((__bf16*)Cv + (size_t)(row0 + row) * N + col0 + cr * 8) = v;
        }
    } else {
        // fp32 path: two 128-row LDS passes (128x256 fp32 = 131072 B each),
        // XOR-swizzled 16B chunks -> coalesced float4 row stores.
        const size_t cofs = (size_t)blockIdx.y * (size_t)M * (size_t)N;
        __syncthreads();   // all waves done with K-loop LDS reads
#pragma unroll
        for (int half = 0; half < 2; ++half) {
            if ((w >> 2) == half) {
#pragma unroll
                for (int fi = 0; fi < 8; ++fi) {
#pragma unroll
                    for (int cf = 0; cf < 4; ++cf) {
                        const int lc = (w & 3) * 64 + cf * 16 + lrow;   // 0..255
                        const float bv = (EPI == 1) ? bias[col0 + lc] : 0.f;
#pragma unroll
                        for (int r = 0; r < 4; ++r) {
                            const int lr2 = fi * 16 + quad * 4 + r;     // 0..127
                            float v = acc[fi][cf][r];
                            if (EPI == 1) v = softplus_f(v + bv);
                            const int ck = (lc >> 2) ^ (lr2 & 63);
                            *(float*)(smem + lr2 * 1024 + ck * 16 + (lc & 3) * 4) = v;
                        }
                    }
                }
            }
            __syncthreads();
#pragma unroll
            for (int it = 0; it < 16; ++it) {
                const int row = it * 8 + w;                             // 0..127
                const int ck  = lane ^ (row & 63);
                floatx4 v = *(const floatx4*)(smem + row * 1024 + ck * 16);
                *(floatx4*)((float*)Cv + cofs +
                            (size_t)(row0 + half * 128 + row) * N + col0 + lane * 4) = v;
            }
            __syncthreads();   // drain reads before next half overwrites
        }
    }
    (void)M;
}

// Sum KS_OUT fp32 partials -> final output (vectorized float4).
__global__ __launch_bounds__(256) void out_reduce(
    const float* __restrict__ parts, float* __restrict__ out)
{
    const size_t i = ((size_t)blockIdx.x * 256 + threadIdx.x) * 4;
    floatx4 s = *(const floatx4*)(parts + i);
#pragma unroll
    for (int kz = 1; kz < KS_OUT; ++kz)
        s += *(const floatx4*)(parts + (size_t)kz * BL * DMODEL + i);
    *(floatx4*)(out + i) = s;
}

// ---------------------------------------------------------------------------
// MFMA bf16 GEMM, 64x128 tile — occupancy variant for small-K / small-N GEMMs
// (dt GEMM: K=64, acc mostly dead).
// 4 waves side by side: wave w = rows 0..63 x cols w*32..w*32+31, acc 4x2.
// ---------------------------------------------------------------------------
template <int EPI>
__global__ __launch_bounds__(256) void gemm_r64(
    const __bf16* __restrict__ A,
    const __bf16* __restrict__ BT,
    void* __restrict__ Cv,
    int M, int N, int K,
    const float* __restrict__ bias)
{
    __shared__ __bf16 Asm[64 * 32];
    __shared__ __bf16 Bsm[128 * 32];

    const int tid  = threadIdx.x;
    const int w    = tid >> 6;
    const int lane = tid & 63;
    const int lrow = lane & 15;
    const int quad = lane >> 4;
    const int row0 = blockIdx.y * 64;
    const int col0 = blockIdx.x * 128;
    const int wc   = w * 32;

    const int ldr = tid >> 2;
    const int ldk = (tid & 3) * 8;
    const __bf16* gA = A  + (size_t)(row0 + ldr) * K + ldk;
    const __bf16* gB = BT + (size_t)(col0 + ldr) * K + ldk;
    const size_t half = (size_t)64 * K;
    __bf16* lA0 = Asm + w * 512;
    __bf16* lB0 = Bsm + w * 512;
    __bf16* lB1 = Bsm + 2048 + w * 512;

    floatx4 acc[4][2];
#pragma unroll
    for (int i = 0; i < 4; ++i)
#pragma unroll
        for (int j = 0; j < 2; ++j)
            acc[i][j] = (floatx4){0.f, 0.f, 0.f, 0.f};

    for (int k0 = 0; k0 < K; k0 += 32) {
        gload_lds16(gA, lA0);
        gload_lds16(gB, lB0);
        gload_lds16(gB + half, lB1);
        gA += 32; gB += 32;
        __syncthreads();

        bf16x8 af[4], bf[2];
#pragma unroll
        for (int t = 0; t < 4; ++t)
            af[t] = *(const bf16x8*)(Asm + (t * 16 + lrow) * 32 + quad * 8);
#pragma unroll
        for (int u = 0; u < 2; ++u)
            bf[u] = *(const bf16x8*)(Bsm + (wc + u * 16 + lrow) * 32 + quad * 8);

#pragma unroll
        for (int ti = 0; ti < 4; ++ti)
#pragma unroll
            for (int tj = 0; tj < 2; ++tj)
                acc[ti][tj] = __builtin_amdgcn_mfma_f32_16x16x32_bf16(
                    af[ti], bf[tj], acc[ti][tj], 0, 0, 0);
        __syncthreads();
    }

#pragma unroll
    for (int ti = 0; ti < 4; ++ti) {
#pragma unroll
        for (int tj = 0; tj < 2; ++tj) {
            int col = col0 + wc + tj * 16 + lrow;
            float bv = (EPI == 1 || EPI == 3) ? bias[col] : 0.f;
#pragma unroll
            for (int r = 0; r < 4; ++r) {
                int row = row0 + ti * 16 + quad * 4 + r;
                float v = acc[ti][tj][r];
                if (EPI == 1 || EPI == 3) v = softplus_f(v + bv);
                if (EPI == 2 || EPI == 3)
                    ((__bf16*)Cv)[(size_t)row * N + col] = (__bf16)v;
                else
                    ((float*)Cv)[(size_t)row * N + col] = v;
            }
        }
    }
}

// ---------------------------------------------------------------------------
// FUSED conv+silu + x_dbl MFMA GEMM.
// Grid (BL/64, KSPLIT). Block tile: 64 rows x KC=256 channels.
// Phase 1: causal depthwise conv + silu on the tile -> xc16 (global) AND
//          Acv (LDS, ALDS-padded rows, 16B-aligned).
// Phase 2: K-loop over KC in 32-steps: B (WxT[128][DINNER]) staged via
//          global_load_lds (2-barrier, as verified in gemm_r64/xdbl_gemm);
//          A fragments read from resident Acv. fp32 partials out.
// ---------------------------------------------------------------------------
__global__ __launch_bounds__(256) void xdbl_fused2(
    const __bf16* __restrict__ xz16,   // [BL, NXZ], xb half
    const float* __restrict__ cwT,     // [4, DINNER]
    const float* __restrict__ cb,      // [DINNER]
    const __bf16* __restrict__ WxT,    // [96(pad128), DINNER] bf16
    __bf16* __restrict__ xc16,         // [BL, DINNER]
    float* __restrict__ parts)         // [KSPLIT, BL, XDP]
{
    __shared__ __bf16 Acv[64 * ALDS];  // 33 KB conv tile
    __shared__ __bf16 Bsm[128 * 32];   // 8 KB B k-slice

    const int tid  = threadIdx.x;
    const int w    = tid >> 6;
    const int lane = tid & 63;
    const int lrow = lane & 15;
    const int quad = lane >> 4;
    const int row0 = blockIdx.x * 64;
    const int kz   = blockIdx.y;
    const int kbeg = kz * KC;
    const int wc   = w * 32;

    // ---- Phase 1: conv tile -> Acv + xc16 (identical math to conv_prep) ----
    {
        const int ct = (tid & 31) * 8;
        const int rt = (tid >> 5) * 8;
        const int d  = kbeg + ct;

        float wreg[DCONV][8];
#pragma unroll
        for (int k = 0; k < DCONV; ++k) {
            float4 a = *(const float4*)(cwT + k * DINNER + d);
            float4 b = *(const float4*)(cwT + k * DINNER + d + 4);
            wreg[k][0]=a.x; wreg[k][1]=a.y; wreg[k][2]=a.z; wreg[k][3]=a.w;
            wreg[k][4]=b.x; wreg[k][5]=b.y; wreg[k][6]=b.z; wreg[k][7]=b.w;
        }
        float bias8[8];
        {
            float4 a = *(const float4*)(cb + d);
            float4 b = *(const float4*)(cb + d + 4);
            bias8[0]=a.x; bias8[1]=a.y; bias8[2]=a.z; bias8[3]=a.w;
            bias8[4]=b.x; bias8[5]=b.y; bias8[6]=b.z; bias8[7]=b.w;
        }

        const bf16x8 zero = {};
        bf16x8 win[DCONV];
        const int tloc0 = (int)((row0 + rt) & (SEQLEN - 1));
#pragma unroll
        for (int j = 0; j < DCONV - 1; ++j)
            win[j] = (tloc0 - 3 + j >= 0)
                ? *(const bf16x8*)(xz16 + (size_t)(row0 + rt - 3 + j) * NXZ + d)
                : zero;

        for (int i = 0; i < 8; ++i) {
            size_t r = (size_t)row0 + rt + i;
            win[DCONV - 1] = *(const bf16x8*)(xz16 + r * NXZ + d);
            bf16x8 o;
#pragma unroll
            for (int j = 0; j < 8; ++j) {
                float acc = bias8[j];
#pragma unroll
                for (int k = 0; k < DCONV; ++k)
                    acc += (float)win[k][j] * wreg[k][j];
                o[j] = (__bf16)silu_f(acc);
            }
            *(bf16x8*)(xc16 + r * DINNER + d) = o;
            *(bf16x8*)(Acv + (rt + i) * ALDS + ct) = o;
#pragma unroll
            for (int k = 0; k < DCONV - 1; ++k)
                win[k] = win[k + 1];
        }
    }
    __syncthreads();

    // ---- Phase 2: MFMA K-loop; B staged per 32-step, A from Acv ----
    const int ldr = tid >> 2;
    const int ldk = (tid & 3) * 8;
    const __bf16* gB = WxT + (size_t)ldr * DINNER + kbeg + ldk;
    const size_t half = (size_t)64 * DINNER;
    __bf16* lB0 = Bsm + w * 512;
    __bf16* lB1 = Bsm + 2048 + w * 512;

    floatx4 acc[4][2];
#pragma unroll
    for (int i = 0; i < 4; ++i)
#pragma unroll
        for (int j = 0; j < 2; ++j)
            acc[i][j] = (floatx4){0.f, 0.f, 0.f, 0.f};

    for (int k0 = 0; k0 < KC; k0 += 32) {
        gload_lds16(gB, lB0);
        gload_lds16(gB + half, lB1);
        gB += 32;
        __syncthreads();

        bf16x8 af[4], bf[2];
#pragma unroll
        for (int t = 0; t < 4; ++t)
            af[t] = *(const bf16x8*)(Acv + (t * 16 + lrow) * ALDS + k0 + quad * 8);
#pragma unroll
        for (int u = 0; u < 2; ++u)
            bf[u] = *(const bf16x8*)(Bsm + (wc + u * 16 + lrow) * 32 + quad * 8);

#pragma unroll
        for (int ti = 0; ti < 4; ++ti)
#pragma unroll
            for (int tj = 0; tj < 2; ++tj)
                acc[ti][tj] = __builtin_amdgcn_mfma_f32_16x16x32_bf16(
                    af[ti], bf[tj], acc[ti][tj], 0, 0, 0);
        __syncthreads();
    }

    const size_t base = (size_t)kz * BL * XDP;
#pragma unroll
    for (int ti = 0; ti < 4; ++ti) {
#pragma unroll
        for (int tj = 0; tj < 2; ++tj) {
            int col = wc + tj * 16 + lrow;
#pragma unroll
            for (int r = 0; r < 4; ++r) {
                int row = row0 + ti * 16 + quad * 4 + r;
                parts[base + (size_t)row * XDP + col] = acc[ti][tj][r];
            }
        }
    }
}

// Reduce KSPLIT partials (stride XDP=128, 96 valid cols) -> xdbl [BL,96] fp32
// + dtlow16 bf16 (cols < 64). float4-vectorized: 24 quads per row.
__global__ __launch_bounds__(256) void xdbl_reduce2(
    const float* __restrict__ parts, float* __restrict__ xdbl,
    __bf16* __restrict__ dtlow16)
{
    const int i4  = blockIdx.x * 256 + threadIdx.x;   // < BL*24
    const int row = i4 / 24;
    const int c4  = i4 - row * 24;
    const float* p = parts + (size_t)row * XDP + c4 * 4;
    floatx4 s = *(const floatx4*)p;
#pragma unroll
    for (int kz = 1; kz < KSPLIT; ++kz)
        s += *(const floatx4*)(p + (size_t)kz * BL * XDP);
    *(floatx4*)(xdbl + (size_t)row * XDBL_N + c4 * 4) = s;
    if (c4 < 16) {
        bf16x4 o = {(__bf16)s.x, (__bf16)s.y, (__bf16)s.z, (__bf16)s.w};
        *(bf16x4*)(dtlow16 + (size_t)row * DTRANK + c4 * 4) = o;
    }
}

// ---------------------------------------------------------------------------
// Merged preprocessing: x->bf16 cast, 4 transpose-casts, conv-w transpose.
// ---------------------------------------------------------------------------
#define NB_CAST  ((BL * DMODEL / 4) / 256)          // 4096
#define NB_WIN   ((NXZ / 32) * (DMODEL / 32))       // 4096
#define NB_WOUT  ((DMODEL / 32) * (DINNER / 32))    // 2048
#define NB_WDT   ((DINNER / 32) * (DTRANK / 32))    // 128
#define NB_CW    ((DCONV * DINNER) / 256)           // 32
#define NB_WXT   ((DINNER / 32) * (XDBL_N / 32))    // 192

__device__ __forceinline__ void transpose_tile(
    const float* __restrict__ src, __bf16* __restrict__ dst, int R, int Cc,
    int bx, int by, int tid, float* tile)
{
    int tx = tid & 31, ty = tid >> 5;   // 32 x 8
    int c0 = bx * 32, r0 = by * 32;
#pragma unroll
    for (int i = 0; i < 32; i += 8)
        tile[(ty + i) * 33 + tx] = src[(size_t)(r0 + ty + i) * Cc + c0 + tx];
    __syncthreads();
#pragma unroll
    for (int i = 0; i < 32; i += 8)
        dst[(size_t)(c0 + ty + i) * R + r0 + tx] = (__bf16)tile[tx * 33 + ty + i];
}

__global__ __launch_bounds__(256) void prep_kernel(
    const float* __restrict__ x,
    const float* __restrict__ W_in,
    const float* __restrict__ W_out,
    const float* __restrict__ W_dt,
    const float* __restrict__ W_x,
    const float* __restrict__ conv_w,
    __bf16* __restrict__ xb16,
    __bf16* __restrict__ WiT16,
    __bf16* __restrict__ WoT16,
    __bf16* __restrict__ WdtT16,
    __bf16* __restrict__ WxT16,
    float* __restrict__ cwT)
{
    __shared__ float tile[32 * 33];
    const int tid = threadIdx.x;
    int bid = blockIdx.x;

    if (bid < NB_CAST) {
        long i = ((long)bid * 256 + tid) * 4;
        float4 v = *(const float4*)(x + i);
        bf16x4 o = {(__bf16)v.x, (__bf16)v.y, (__bf16)v.z, (__bf16)v.w};
        *(bf16x4*)(xb16 + i) = o;
        return;
    }
    bid -= NB_CAST;
    if (bid < NB_WIN) {
        transpose_tile(W_in, WiT16, DMODEL, NXZ,
                       bid % (NXZ / 32), bid / (NXZ / 32), tid, tile);
        return;
    }
    bid -= NB_WIN;
    if (bid < NB_WOUT) {
        transpose_tile(W_out, WoT16, DINNER, DMODEL,
                       bid % (DMODEL / 32), bid / (DMODEL / 32), tid, tile);
        return;
    }
    bid -= NB_WOUT;
    if (bid < NB_WDT) {
        transpose_tile(W_dt, WdtT16, DTRANK, DINNER,
                       bid % (DINNER / 32), bid / (DINNER / 32), tid, tile);
        return;
    }
    bid -= NB_WDT;
    if (bid < NB_CW) {
        int i = bid * 256 + tid;                  // < DCONV*DINNER
        int k = i / DINNER, d = i % DINNER;
        cwT[i] = conv_w[d * DCONV + k];
        return;
    }
    bid -= NB_CW;
    {
        transpose_tile(W_x, WxT16, DINNER, XDBL_N,
                       bid % (XDBL_N / 32), bid / (XDBL_N / 32), tid, tile);
    }
}

// ---------------------------------------------------------------------------
// Chunked parallel scan (dt bf16, LCH=32, exp2-prescaled decay).
// B/C rows of the chunk staged once in LDS (broadcast ds_read per t).
// 2-channel ILP: each thread runs TWO independent h-chains (d0, d0+1024) —
// B/C reads, loop control and addresses amortize; exp2 latency of one chain
// hides under the other's FMAs. Grid.x halves vs 1-chain (512 blocks).
// Per-channel math order identical to the 1-chain version.
// ---------------------------------------------------------------------------
__global__ __launch_bounds__(256) void scan_pass1(
    const __bf16* __restrict__ dt16,
    const __bf16* __restrict__ xc16,
    const float* __restrict__ xdbl,
    const float* __restrict__ A_log,
    float* __restrict__ sums_h,
    float* __restrict__ sums_p)
{
    __shared__ __align__(16) float Bs[LCH][16];   // 2 KB: B rows of this chunk

    const int d0 = blockIdx.x * 256 + threadIdx.x;   // [0, 1024)
    const int d1 = d0 + DINNER / 2;
    const int bc = blockIdx.y;
    const int b  = bc / NCHUNK, c = bc % NCHUNK;
    const long r0 = (long)b * SEQLEN + (long)c * LCH;

    // stage B slice: 32 rows x 16 floats, 128 threads x 1 float4
    if (threadIdx.x < LCH * 4) {
        const int row = threadIdx.x >> 2, c4 = threadIdx.x & 3;
        *(float4*)&Bs[row][c4 * 4] =
            *(const float4*)(xdbl + (size_t)(r0 + row) * XDBL_N + DTRANK + c4 * 4);
    }

    float Ad0[DSTATE], Ad1[DSTATE];
    {
        const float4* a0 = (const float4*)(A_log + d0 * DSTATE);
        const float4* a1 = (const float4*)(A_log + d1 * DSTATE);
#pragma unroll
        for (int q = 0; q < 4; ++q) {
            float4 v0 = a0[q], v1 = a1[q];
            Ad0[q*4+0] = -__expf(v0.x) * 1.44269504f;
            Ad0[q*4+1] = -__expf(v0.y) * 1.44269504f;
            Ad0[q*4+2] = -__expf(v0.z) * 1.44269504f;
            Ad0[q*4+3] = -__expf(v0.w) * 1.44269504f;
            Ad1[q*4+0] = -__expf(v1.x) * 1.44269504f;
            Ad1[q*4+1] = -__expf(v1.y) * 1.44269504f;
            Ad1[q*4+2] = -__expf(v1.z) * 1.44269504f;
            Ad1[q*4+3] = -__expf(v1.w) * 1.44269504f;
        }
    }
    __syncthreads();

    float h0[DSTATE] = {}, h1[DSTATE] = {};
    float Sdt0 = 0.f, Sdt1 = 0.f;

#pragma unroll 4
    for (int t = 0; t < LCH; ++t) {
        long r = r0 + t;
        float dtv0 = (float)dt16[r * DINNER + d0];
        float dtv1 = (float)dt16[r * DINNER + d1];
        float xv0  = (float)xc16[r * DINNER + d0];
        float xv1  = (float)xc16[r * DINNER + d1];
        float xdt0 = xv0 * dtv0, xdt1 = xv1 * dtv1;
        Sdt0 += dtv0; Sdt1 += dtv1;
        const float4* bv = (const float4*)Bs[t];
        float4 B0 = bv[0], B1 = bv[1], B2 = bv[2], B3 = bv[3];
        const float Bn[DSTATE] = {B0.x,B0.y,B0.z,B0.w, B1.x,B1.y,B1.z,B1.w,
                                  B2.x,B2.y,B2.z,B2.w, B3.x,B3.y,B3.z,B3.w};
#pragma unroll
        for (int n = 0; n < DSTATE; ++n) {
            float dA0 = fast_exp2(Ad0[n] * dtv0);
            float dA1 = fast_exp2(Ad1[n] * dtv1);
            h0[n] = h0[n] * dA0 + xdt0 * Bn[n];
            h1[n] = h1[n] * dA1 + xdt1 * Bn[n];
        }
    }

    const long rowbase = (long)bc * DSTATE;
#pragma unroll
    for (int n = 0; n < DSTATE; ++n) {
        sums_h[(rowbase + n) * DINNER + d0] = h0[n];
        sums_h[(rowbase + n) * DINNER + d1] = h1[n];
        sums_p[(rowbase + n) * DINNER + d0] = fast_exp2(Ad0[n] * Sdt0);
        sums_p[(rowbase + n) * DINNER + d1] = fast_exp2(Ad1[n] * Sdt1);
    }
}

__global__ __launch_bounds__(256) void scan_combine(
    float* __restrict__ sums_h, float* __restrict__ sums_p)
{
    int u = blockIdx.x * 256 + threadIdx.x;
    int d = u & (DINNER - 1);
    int n = (u >> 11) & (DSTATE - 1);
    int b = u >> 15;
    float hg = 0.f;
    for (int c = 0; c < NCHUNK; ++c) {
        long row = (long)(b * NCHUNK + c) * DSTATE + n;
        float p  = sums_p[row * DINNER + d];
        float hl = sums_h[row * DINNER + d];
        sums_p[row * DINNER + d] = hg;   // hstart for this chunk
        hg = p * hg + hl;
    }
}

// Pass 3: replay from hstart, fused gate, emit bf16 gated activation.
// Same 2-channel ILP structure as pass1.
__global__ __launch_bounds__(256) void scan_pass3(
    const __bf16* __restrict__ dt16,
    const __bf16* __restrict__ xc16,
    const float* __restrict__ xdbl,
    const float* __restrict__ A_log,
    const __bf16* __restrict__ xz16,  // z half at col DINNER+d
    const float* __restrict__ sums_p, // hstart
    const float* __restrict__ Dp,
    __bf16* __restrict__ gated)       // [BL, DINNER] bf16
{
    __shared__ __align__(16) float BCs[LCH][32];  // 4 KB: B+C rows of chunk

    const int d0 = blockIdx.x * 256 + threadIdx.x;   // [0, 1024)
    const int d1 = d0 + DINNER / 2;
    const int bc = blockIdx.y;
    const int b  = bc / NCHUNK, c = bc % NCHUNK;
    const long r0 = (long)b * SEQLEN + (long)c * LCH;

    // stage B+C slice: 32 rows x 32 floats, 256 threads x 1 float4
    {
        const int row = threadIdx.x >> 3, c4 = threadIdx.x & 7;
        *(float4*)&BCs[row][c4 * 4] =
            *(const float4*)(xdbl + (size_t)(r0 + row) * XDBL_N + DTRANK + c4 * 4);
    }

    float Ad0[DSTATE], Ad1[DSTATE];
    {
        const float4* a0 = (const float4*)(A_log + d0 * DSTATE);
        const float4* a1 = (const float4*)(A_log + d1 * DSTATE);
#pragma unroll
        for (int q = 0; q < 4; ++q) {
            float4 v0 = a0[q], v1 = a1[q];
            Ad0[q*4+0] = -__expf(v0.x) * 1.44269504f;
            Ad0[q*4+1] = -__expf(v0.y) * 1.44269504f;
            Ad0[q*4+2] = -__expf(v0.z) * 1.44269504f;
            Ad0[q*4+3] = -__expf(v0.w) * 1.44269504f;
            Ad1[q*4+0] = -__expf(v1.x) * 1.44269504f;
            Ad1[q*4+1] = -__expf(v1.y) * 1.44269504f;
            Ad1[q*4+2] = -__expf(v1.z) * 1.44269504f;
            Ad1[q*4+3] = -__expf(v1.w) * 1.44269504f;
        }
    }

    float h0[DSTATE], h1[DSTATE];
    const long rowbase = (long)bc * DSTATE;
#pragma unroll
    for (int n = 0; n < DSTATE; ++n) {
        h0[n] = sums_p[(rowbase + n) * DINNER + d0];
        h1[n] = sums_p[(rowbase + n) * DINNER + d1];
    }

    const float Dv0 = Dp[d0], Dv1 = Dp[d1];
    __syncthreads();

#pragma unroll 2
    for (int t = 0; t < LCH; ++t) {
        long r = r0 + t;
        float dtv0 = (float)dt16[r * DINNER + d0];
        float dtv1 = (float)dt16[r * DINNER + d1];
        float xv0  = (float)xc16[r * DINNER + d0];
        float xv1  = (float)xc16[r * DINNER + d1];
        float xdt0 = xv0 * dtv0, xdt1 = xv1 * dtv1;
        const float4* bv = (const float4*)BCs[t];
        float4 B0 = bv[0], B1 = bv[1], B2 = bv[2], B3 = bv[3];
        float4 C0 = bv[4], C1 = bv[5], C2 = bv[6], C3 = bv[7];
        const float Bn[DSTATE] = {B0.x,B0.y,B0.z,B0.w, B1.x,B1.y,B1.z,B1.w,
                                  B2.x,B2.y,B2.z,B2.w, B3.x,B3.y,B3.z,B3.w};
        const float Cn[DSTATE] = {C0.x,C0.y,C0.z,C0.w, C1.x,C1.y,C1.z,C1.w,
                                  C2.x,C2.y,C2.z,C2.w, C3.x,C3.y,C3.z,C3.w};
        float y0 = 0.f, y1 = 0.f;
#pragma unroll
        for (int n = 0; n < DSTATE; ++n) {
            float dA0 = fast_exp2(Ad0[n] * dtv0);
            float dA1 = fast_exp2(Ad1[n] * dtv1);
            h0[n] = h0[n] * dA0 + xdt0 * Bn[n];
            h1[n] = h1[n] * dA1 + xdt1 * Bn[n];
            y0 += h0[n] * Cn[n];
            y1 += h1[n] * Cn[n];
        }
        float z0 = (float)xz16[r * NXZ + DINNER + d0];
        float z1 = (float)xz16[r * NXZ + DINNER + d1];
        gated[r * DINNER + d0] = (__bf16)((y0 + xv0 * Dv0) * silu_f(z0));
        gated[r * DINNER + d1] = (__bf16)((y1 + xv1 * Dv1) * silu_f(z1));
    }
}

// ---------------------------------------------------------------------------
extern "C" void kernel_launch(void* const* d_in, const int* in_sizes, int n_in,
                              void* d_out, int out_size, void* d_ws, size_t ws_size,
                              hipStream_t stream) {
    const float* x      = (const float*)d_in[0];
    const float* W_in   = (const float*)d_in[1];
    const float* conv_w = (const float*)d_in[2];
    const float* conv_b = (const float*)d_in[3];
    const float* W_x    = (const float*)d_in[4];
    const float* W_dt   = (const float*)d_in[5];
    const float* b_dt   = (const float*)d_in[6];
    const float* A_log  = (const float*)d_in[7];
    const float* Dp     = (const float*)d_in[8];
    const float* W_out  = (const float*)d_in[9];
    float* out = (float*)d_out;

    // Workspace layout (~141 MB):
    __bf16* xz16    = (__bf16*)d_ws;                    // BL*NXZ
    __bf16* xc16    = xz16 + (long)BL * NXZ;            // BL*DINNER
    __bf16* dt16    = xc16 + (long)BL * DINNER;         // BL*DINNER
    __bf16* gated16 = dt16 + (long)BL * DINNER;         // BL*DINNER
    __bf16* WoT16   = gated16 + (long)BL * DINNER;      // DINNER*DMODEL
    __bf16* WdtT16  = WoT16 + (long)DINNER * DMODEL;    // DINNER*DTRANK
    __bf16* dtlow16 = WdtT16 + (long)DINNER * DTRANK;   // BL*DTRANK
    __bf16* xb16    = dtlow16 + (long)BL * DTRANK;      // BL*DMODEL
    __bf16* WiT16   = xb16 + (long)BL * DMODEL;         // NXZ*DMODEL
    float*  xdbl    = (float*)(WiT16 + (long)NXZ * DMODEL);  // BL*96
    float*  cwT     = xdbl + (long)BL * XDBL_N;         // 4*DINNER
    float*  scratch = cwT + (long)DCONV * DINNER;       // partials, then sums
    float*  sums_h  = scratch;                          // 16.8 MB
    float*  sums_p  = scratch + (long)BATCH * NCHUNK * DSTATE * DINNER;
    // WxT16 [128][DINNER] bf16 (512 KB) lives at the sums_p base: written by
    // prep, read by xdbl_fused2 (whose partials occupy only the sums_h half
    // of scratch: KSPLIT*BL*XDP*4B = 16,777,216 B = sums_h size exactly);
    // sums_p is first written by scan_pass1, after WxT16 is dead.
    __bf16* WxT16 = (__bf16*)sums_p;
    // Out-GEMM split-K partials: overlay the xz16|xc16|dt16 region, which is
    // dead after scan_pass3. Size = KS_OUT*BL*DMODEL*4B = 67,108,864 B; the
    // region [0, gated16) is exactly (BL*NXZ + 2*BL*DINNER)*2B = 67,108,864 B.
    float* outparts = (float*)d_ws;

    dim3 blk(256);

    // 0) merged prep: cast + 4 weight transposes + conv-w transpose
    prep_kernel<<<dim3(NB_CAST + NB_WIN + NB_WOUT + NB_WDT + NB_CW + NB_WXT),
                  blk, 0, stream>>>(
        x, W_in, W_out, W_dt, W_x, conv_w, xb16, WiT16, WoT16, WdtT16, WxT16, cwT);

    // 1) xz = x @ W_in   (256x256 8-phase MFMA template, bf16 LDS-epilogue)
    gemm_bt_256<2><<<dim3((BL / 256) * (NXZ / 256)), dim3(512), 0, stream>>>(
        xb16, WiT16, xz16, BL, NXZ, DMODEL, DMODEL, nullptr);

    // 2+3) FUSED conv+silu (-> xc16) + x_dbl MFMA split-K partials, + reduce
    xdbl_fused2<<<dim3(BL / 64, KSPLIT), blk, 0, stream>>>(
        xz16, cwT, conv_b, WxT16, xc16, scratch);
    xdbl_reduce2<<<dim3((BL * 24) / 256), blk, 0, stream>>>(scratch, xdbl, dtlow16);

    // 4) dt = softplus(dt_low @ W_dt + b_dt)   (64-row tile, 1024 blocks)
    gemm_r64<3><<<dim3(DINNER / 128, BL / 64), blk, 0, stream>>>(
        dtlow16, WdtT16, dt16, BL, DINNER, DTRANK, b_dt);

    // 5) chunked scan (2-channel ILP): pass1 -> combine -> pass3
    {
        dim3 grid1(DINNER / 2 / 256, BATCH * NCHUNK);   // (4, 128)
        scan_pass1<<<grid1, blk, 0, stream>>>(dt16, xc16, xdbl, A_log, sums_h, sums_p);
        scan_combine<<<dim3((BATCH * DSTATE * DINNER) / 256), blk, 0, stream>>>(
            sums_h, sums_p);
        scan_pass3<<<grid1, blk, 0, stream>>>(dt16, xc16, xdbl, A_log, xz16,
                                              sums_p, Dp, gated16);
    }
    // 7) out = gated @ W_out: split-K x4 8-phase 256^2 partials (grid 64x4 =
    //    256 blocks = 1/CU, fp32 LDS-epilogue) + fp32 reduce.
    gemm_bt_256<0><<<dim3((BL / 256) * (DMODEL / 256), KS_OUT), dim3(512), 0, stream>>>(
        gated16, WoT16, outparts, BL, DMODEL, KCO, DINNER, nullptr);
    out_reduce<<<dim3((BL * DMODEL) / 1024), blk, 0, stream>>>(outparts, out);

    (void)in_sizes; (void)n_in; (void)out_size; (void)ws_size;
}

// Round 12
// 271.290 us; speedup vs baseline: 1.0175x; 1.0175x over previous
//
#include <hip/hip_runtime.h>
#include <hip/hip_bf16.h>

// Problem constants (MambaBlock): B=2, L=2048, d_model=1024, d_inner=2048,
// d_conv=4, dt_rank=64, d_state=16. All inputs/output float32 (per reference).

#define BATCH   2
#define SEQLEN  2048
#define DMODEL  1024
#define DINNER  2048
#define DCONV   4
#define DTRANK  64
#define DSTATE  16
#define BL      (BATCH * SEQLEN)         // 4096
#define NXZ     (2 * DINNER)             // 4096
#define XDBL_N  (DTRANK + 2 * DSTATE)    // 96
#define LCH     32                       // chunk length for parallel scan
#define NCHUNK  (SEQLEN / LCH)           // 64 chunks per sequence
#define KSPLIT  8                        // channel split for conv/x_dbl blocks
#define KC      (DINNER / KSPLIT)        // 256
#define KS_OUT  4                        // split-K for the out GEMM
#define KCO     (DINNER / KS_OUT)        // 512
#define XDP     128                      // padded partial width for x_dbl
#define ALDS    264                      // padded LDS row stride (bf16, 16B-aligned rows)

typedef __bf16 bf16x8 __attribute__((ext_vector_type(8)));
typedef __bf16 bf16x4 __attribute__((ext_vector_type(4)));
typedef float  floatx4 __attribute__((ext_vector_type(4)));

__device__ __forceinline__ float silu_f(float v) {
    return v / (1.f + __expf(-v));
}

// Fast softplus via native v_exp_f32/v_log_f32 (error ~1e-7, << bf16 noise).
__device__ __forceinline__ float softplus_f(float v) {
    return (v > 20.f) ? v : __logf(1.f + __expf(v));
}

// Native base-2 exp (v_exp_f32). __exp2f collides with a glibc macro.
__device__ __forceinline__ float fast_exp2(float v) {
    return __builtin_amdgcn_exp2f(v);
}

__device__ __forceinline__ void gload_lds16(const __bf16* g, __bf16* l) {
    __builtin_amdgcn_global_load_lds(
        (const __attribute__((address_space(1))) void*)g,
        (__attribute__((address_space(3))) void*)l, 16, 0, 0);
}

// counted vmcnt wait; "memory" clobber pins C++ LDS reads on the correct side
#define VMW(n) asm volatile("s_waitcnt vmcnt(" #n ")" ::: "memory")
#define BARX() __builtin_amdgcn_s_barrier()

// ---------------------------------------------------------------------------
// 256x256 8-phase bf16 GEMM (T1+T2+T3+T4+T5 template, plain HIP).
//   BM=BN=256, BK=64, 512 threads = 8 waves (2M x 4N), 128x64 out per wave.
//   LDS 128 KiB: 2 dbuf x { A: 2 half-slots 128x64, B: 2 half-slots 128x64 }.
//   K is the LOOP length (must be even multiple of 64, >= 256); lda is the
//   K-dim stride of both A and BT. blockIdx.y selects a K-split chunk
//   (kbase = blockIdx.y * K); fp32 stores go to partial blockIdx.y * M * N.
//   Waits: vmcnt(8) end of ph1/ph5, vmcnt(6) end of ph3/ph7 (never 0 in
//   the main loop); every LDS overwrite is >=1 barrier after its last read.
//   Epilogues: smem (dead after K-loop) reused as a C-tile staging buffer
//   (XOR-swizzled 16B chunks) -> coalesced stores. bf16: full tile, bf16x8
//   row stores. fp32: two 128-row passes, float4 row stores (1KB/wave-instr).
// EPI: 0 = fp32 store; 1 = softplus fp32; 2 = bf16 store; 3 = softplus bf16.
// ---------------------------------------------------------------------------
template <int BUF, int QA>
__device__ __forceinline__ void rdA(const char* rA, bf16x8 (&aF)[4][2]) {
#pragma unroll
    for (int j = 0; j < 4; ++j) {
        aF[j][0] = *(const bf16x8*)(rA + BUF * 65536 + ((QA * 4 + j) * 2 + 0) * 1024);
        aF[j][1] = *(const bf16x8*)(rA + BUF * 65536 + ((QA * 4 + j) * 2 + 1) * 1024);
    }
}

template <int BUF, int QB>
__device__ __forceinline__ void rdB(const char* rB, bf16x8 (&bF)[2][2]) {
#pragma unroll
    for (int f = 0; f < 2; ++f) {
        bF[f][0] = *(const bf16x8*)(rB + BUF * 65536 + QB * 8192 + f * 2048 + 0);
        bF[f][1] = *(const bf16x8*)(rB + BUF * 65536 + QB * 8192 + f * 2048 + 1024);
    }
}

template <int QA, int QB>
__device__ __forceinline__ void mf16(const bf16x8 (&aF)[4][2], const bf16x8 (&bF)[2][2],
                                     floatx4 (&acc)[8][4]) {
    __builtin_amdgcn_s_setprio(1);
#pragma unroll
    for (int ks = 0; ks < 2; ++ks)
#pragma unroll
        for (int j = 0; j < 4; ++j)
#pragma unroll
            for (int f = 0; f < 2; ++f)
                acc[QA * 4 + j][QB * 2 + f] = __builtin_amdgcn_mfma_f32_16x16x32_bf16(
                    aF[j][ks], bF[f][ks], acc[QA * 4 + j][QB * 2 + f], 0, 0, 0);
    __builtin_amdgcn_s_setprio(0);
}

template <int BUF, int QA>
__device__ __forceinline__ void stA2(const __bf16* gAs, char* sm, int lda, int w, int t) {
    gload_lds16(gAs + (size_t)(QA * 64) * lda + t * 64,
                (__bf16*)(sm + BUF * 65536 + QA * 8192 + w * 1024));
    gload_lds16(gAs + (size_t)(128 + QA * 64) * lda + t * 64,
                (__bf16*)(sm + BUF * 65536 + 16384 + QA * 8192 + w * 1024));
}

template <int BUF, int QB>
__device__ __forceinline__ void stB2(const __bf16* gBs, char* sm, int lda, int w, int t) {
    gload_lds16(gBs + (size_t)(QB * 32) * lda + t * 64,
                (__bf16*)(sm + BUF * 65536 + 32768 + QB * 8192 + w * 1024));
    gload_lds16(gBs + (size_t)(128 + QB * 32) * lda + t * 64,
                (__bf16*)(sm + BUF * 65536 + 32768 + 16384 + QB * 8192 + w * 1024));
}

template <int EPI>
__global__ __launch_bounds__(512, 2) void gemm_bt_256(
    const __bf16* __restrict__ A,
    const __bf16* __restrict__ BT,
    void* __restrict__ Cv,
    int M, int N, int K, int lda,
    const float* __restrict__ bias)
{
    __shared__ __align__(16) char smem[131072];

    const int tid  = threadIdx.x;
    const int w    = tid >> 6;
    const int lane = tid & 63;

    // XCD-aware bijective block swizzle (gridDim.x % 8 == 0).
    const int cpx = gridDim.x >> 3;
    const int swz = (blockIdx.x & 7) * cpx + (blockIdx.x >> 3);
    const int ntn = N >> 8;
    const int row0 = (swz / ntn) << 8;
    const int col0 = (swz % ntn) << 8;
    const int kbase = blockIdx.y * K;          // K-split chunk base

    // ---- stage-side decode (thread-constant): physical granule P=tid maps to
    // logical (row, col) so global src is pre-inverse-swizzled; LDS dest linear.
    const int P     = tid;
    const int rr    = (P >> 2) & 15;
    const int qq    = (P & 3) ^ (2 * ((P >> 5) & 1));
    const int colE  = (((P >> 6) & 1) * 4 + qq) * 8;
    const int rgP   = P >> 7;                              // 0..3
    const int rowAu = rgP * 16 + rr;                       // within 64-row qa unit
    const int rowBu = (rgP >> 1) * 64 + (rgP & 1) * 16 + rr; // within slot (+qb*32 at use)

    const __bf16* gAs = A  + (size_t)(row0 + rowAu) * lda + kbase + colE;
    const __bf16* gBs = BT + (size_t)(col0 + rowBu) * lda + kbase + colE;
    char* sm = smem;

    // ---- read-side swizzled lane offset (matches stage decode; involution)
    const int lsw = ((lane & 15) * 4 + ((lane >> 4) ^ (2 * ((lane >> 3) & 1)))) * 16;
    const char* rA = smem + (w >> 2) * 16384 + lsw;
    const char* rB = smem + 32768 + ((w & 3) >> 1) * 16384 + ((w & 3) & 1) * 4096 + lsw;

    floatx4 acc[8][4];
#pragma unroll
    for (int i = 0; i < 8; ++i)
#pragma unroll
        for (int j = 0; j < 4; ++j)
            acc[i][j] = (floatx4){0.f, 0.f, 0.f, 0.f};
    bf16x8 aF[4][2], bF[2][2];

    const int NT = K >> 6;       // 64-wide K tiles (even, >= 4)
    const int NI = NT >> 1;

    // ---- prologue: 12 loads; vmcnt(6) leaves {Aqa1(t0), Aqa0(t1), Bqb1(t1)}
    stA2<0, 0>(gAs, sm, lda, w, 0);
    stB2<0, 0>(gBs, sm, lda, w, 0);
    stB2<0, 1>(gBs, sm, lda, w, 0);
    stA2<0, 1>(gAs, sm, lda, w, 0);
    stA2<1, 0>(gAs, sm, lda, w, 1);
    stB2<1, 1>(gBs, sm, lda, w, 1);
    VMW(6);
    BARX();

    for (int i = 0; i < NI - 1; ++i) {
        const int t1 = 2 * i + 1, t2 = 2 * i + 2, t3 = 2 * i + 3;
        // ph0: tile 2i (buf0), q=(0,0)
        rdA<0, 0>(rA, aF); rdB<0, 0>(rB, bF);
        stB2<1, 0>(gBs, sm, lda, w, t1);
        BARX(); mf16<0, 0>(aF, bF, acc); BARX();
        // ph1: (0,1)
        rdB<0, 1>(rB, bF);
        stA2<1, 1>(gAs, sm, lda, w, t1);
        BARX(); mf16<0, 1>(aF, bF, acc); VMW(8); BARX();
        // ph2: (1,1)
        rdA<0, 1>(rA, aF);
        stA2<0, 0>(gAs, sm, lda, w, t2);
        BARX(); mf16<1, 1>(aF, bF, acc); BARX();
        // ph3: (1,0)  (re-read B qb0)
        rdB<0, 0>(rB, bF);
        stB2<0, 1>(gBs, sm, lda, w, t2);
        BARX(); mf16<1, 0>(aF, bF, acc); VMW(6); BARX();
        // ph4: tile 2i+1 (buf1), q=(0,0)
        rdA<1, 0>(rA, aF); rdB<1, 0>(rB, bF);
        stB2<0, 0>(gBs, sm, lda, w, t2);
        BARX(); mf16<0, 0>(aF, bF, acc); BARX();
        // ph5: (0,1)
        rdB<1, 1>(rB, bF);
        stA2<0, 1>(gAs, sm, lda, w, t2);
        BARX(); mf16<0, 1>(aF, bF, acc); VMW(8); BARX();
        // ph6: (1,1)
        rdA<1, 1>(rA, aF);
        stA2<1, 0>(gAs, sm, lda, w, t3);
        BARX(); mf16<1, 1>(aF, bF, acc); BARX();
        // ph7: (1,0)
        rdB<1, 0>(rB, bF);
        stB2<1, 1>(gBs, sm, lda, w, t3);
        BARX(); mf16<1, 0>(aF, bF, acc); VMW(6); BARX();
    }
    // ---- tail iteration (tiles NT-2, NT-1): no further stages; drain 2 -> 0
    {
        const int t1 = NT - 1;
        rdA<0, 0>(rA, aF); rdB<0, 0>(rB, bF);
        stB2<1, 0>(gBs, sm, lda, w, t1);
        BARX(); mf16<0, 0>(aF, bF, acc); BARX();
        rdB<0, 1>(rB, bF);
        stA2<1, 1>(gAs, sm, lda, w, t1);
        BARX(); mf16<0, 1>(aF, bF, acc); VMW(8); BARX();
        rdA<0, 1>(rA, aF);
        BARX(); mf16<1, 1>(aF, bF, acc); BARX();
        rdB<0, 0>(rB, bF);
        BARX(); mf16<1, 0>(aF, bF, acc); VMW(2); BARX();
        rdA<1, 0>(rA, aF); rdB<1, 0>(rB, bF);
        BARX(); mf16<0, 0>(aF, bF, acc); BARX();
        rdB<1, 1>(rB, bF);
        BARX(); mf16<0, 1>(aF, bF, acc); VMW(0); BARX();
        rdA<1, 1>(rA, aF);
        BARX(); mf16<1, 1>(aF, bF, acc); BARX();
        rdB<1, 0>(rB, bF);
        BARX(); mf16<1, 0>(aF, bF, acc);
    }

    // ---- epilogue: acc fragment layout col=lane&15, row=(lane>>4)*4+reg
    const int lrow = lane & 15, quad = lane >> 4;

    if (EPI == 2 || EPI == 3) {
        // bf16 path: stage full 256x256 bf16 tile through smem (131072 B,
        // XOR-swizzled 16B chunks) -> coalesced bf16x8 row stores.
        __syncthreads();   // all waves done with K-loop LDS reads
#pragma unroll
        for (int fi = 0; fi < 8; ++fi) {
#pragma unroll
            for (int cf = 0; cf < 4; ++cf) {
                const int lc = (w & 3) * 64 + cf * 16 + lrow;       // 0..255
                const float bv = (EPI == 3) ? bias[col0 + lc] : 0.f;
#pragma unroll
                for (int r = 0; r < 4; ++r) {
                    const int lr = (w >> 2) * 128 + fi * 16 + quad * 4 + r;  // 0..255
                    float v = acc[fi][cf][r];
                    if (EPI == 3) v = softplus_f(v + bv);
                    const int ck = (lc >> 3) ^ ((lr >> 2) & 7);
                    *(__bf16*)(smem + lr * 512 + ck * 16 + (lc & 7) * 2) = (__bf16)v;
                }
            }
        }
        __syncthreads();
#pragma unroll
        for (int it = 0; it < 16; ++it) {
            const int row = it * 16 + w * 2 + (lane >> 5);          // 0..255
            const int cr  = lane & 31;
            const int ck  = cr ^ ((row >> 2) & 7);
            bf16x8 v = *(const bf16x8*)(smem + row * 512 + ck * 16);
            *(bf16x8*)((__bf16*)Cv + (size_t)(row0 + row) * N + col0 + cr * 8) = v;
        }
    } else {
        // fp32 path: two 128-row LDS passes (128x256 fp32 = 131072 B each),
        // XOR-swizzled 16B chunks -> coalesced float4 row stores.
        const size_t cofs = (size_t)blockIdx.y * (size_t)M * (size_t)N;
        __syncthreads();   // all waves done with K-loop LDS reads
#pragma unroll
        for (int half = 0; half < 2; ++half) {
            if ((w >> 2) == half) {
#pragma unroll
                for (int fi = 0; fi < 8; ++fi) {
#pragma unroll
                    for (int cf = 0; cf < 4; ++cf) {
                        const int lc = (w & 3) * 64 + cf * 16 + lrow;   // 0..255
                        const float bv = (EPI == 1) ? bias[col0 + lc] : 0.f;
#pragma unroll
                        for (int r = 0; r < 4; ++r) {
                            const int lr2 = fi * 16 + quad * 4 + r;     // 0..127
                            float v = acc[fi][cf][r];
                            if (EPI == 1) v = softplus_f(v + bv);
                            const int ck = (lc >> 2) ^ (lr2 & 63);
                            *(float*)(smem + lr2 * 1024 + ck * 16 + (lc & 3) * 4) = v;
                        }
                    }
                }
            }
            __syncthreads();
#pragma unroll
            for (int it = 0; it < 16; ++it) {
                const int row = it * 8 + w;                             // 0..127
                const int ck  = lane ^ (row & 63);
                floatx4 v = *(const floatx4*)(smem + row * 1024 + ck * 16);
                *(floatx4*)((float*)Cv + cofs +
                            (size_t)(row0 + half * 128 + row) * N + col0 + lane * 4) = v;
            }
            __syncthreads();   // drain reads before next half overwrites
        }
    }
    (void)M;
}

// Sum KS_OUT fp32 partials -> final output (vectorized float4).
__global__ __launch_bounds__(256) void out_reduce(
    const float* __restrict__ parts, float* __restrict__ out)
{
    const size_t i = ((size_t)blockIdx.x * 256 + threadIdx.x) * 4;
    floatx4 s = *(const floatx4*)(parts + i);
#pragma unroll
    for (int kz = 1; kz < KS_OUT; ++kz)
        s += *(const floatx4*)(parts + (size_t)kz * BL * DMODEL + i);
    *(floatx4*)(out + i) = s;
}

// ---------------------------------------------------------------------------
// MFMA bf16 GEMM, 64x128 tile — occupancy variant for small-K / small-N GEMMs
// (dt GEMM: K=64, acc mostly dead).
// 4 waves side by side: wave w = rows 0..63 x cols w*32..w*32+31, acc 4x2.
// ---------------------------------------------------------------------------
template <int EPI>
__global__ __launch_bounds__(256) void gemm_r64(
    const __bf16* __restrict__ A,
    const __bf16* __restrict__ BT,
    void* __restrict__ Cv,
    int M, int N, int K,
    const float* __restrict__ bias)
{
    __shared__ __bf16 Asm[64 * 32];
    __shared__ __bf16 Bsm[128 * 32];

    const int tid  = threadIdx.x;
    const int w    = tid >> 6;
    const int lane = tid & 63;
    const int lrow = lane & 15;
    const int quad = lane >> 4;
    const int row0 = blockIdx.y * 64;
    const int col0 = blockIdx.x * 128;
    const int wc   = w * 32;

    const int ldr = tid >> 2;
    const int ldk = (tid & 3) * 8;
    const __bf16* gA = A  + (size_t)(row0 + ldr) * K + ldk;
    const __bf16* gB = BT + (size_t)(col0 + ldr) * K + ldk;
    const size_t half = (size_t)64 * K;
    __bf16* lA0 = Asm + w * 512;
    __bf16* lB0 = Bsm + w * 512;
    __bf16* lB1 = Bsm + 2048 + w * 512;

    floatx4 acc[4][2];
#pragma unroll
    for (int i = 0; i < 4; ++i)
#pragma unroll
        for (int j = 0; j < 2; ++j)
            acc[i][j] = (floatx4){0.f, 0.f, 0.f, 0.f};

    for (int k0 = 0; k0 < K; k0 += 32) {
        gload_lds16(gA, lA0);
        gload_lds16(gB, lB0);
        gload_lds16(gB + half, lB1);
        gA += 32; gB += 32;
        __syncthreads();

        bf16x8 af[4], bf[2];
#pragma unroll
        for (int t = 0; t < 4; ++t)
            af[t] = *(const bf16x8*)(Asm + (t * 16 + lrow) * 32 + quad * 8);
#pragma unroll
        for (int u = 0; u < 2; ++u)
            bf[u] = *(const bf16x8*)(Bsm + (wc + u * 16 + lrow) * 32 + quad * 8);

#pragma unroll
        for (int ti = 0; ti < 4; ++ti)
#pragma unroll
            for (int tj = 0; tj < 2; ++tj)
                acc[ti][tj] = __builtin_amdgcn_mfma_f32_16x16x32_bf16(
                    af[ti], bf[tj], acc[ti][tj], 0, 0, 0);
        __syncthreads();
    }

#pragma unroll
    for (int ti = 0; ti < 4; ++ti) {
#pragma unroll
        for (int tj = 0; tj < 2; ++tj) {
            int col = col0 + wc + tj * 16 + lrow;
            float bv = (EPI == 1 || EPI == 3) ? bias[col] : 0.f;
#pragma unroll
            for (int r = 0; r < 4; ++r) {
                int row = row0 + ti * 16 + quad * 4 + r;
                float v = acc[ti][tj][r];
                if (EPI == 1 || EPI == 3) v = softplus_f(v + bv);
                if (EPI == 2 || EPI == 3)
                    ((__bf16*)Cv)[(size_t)row * N + col] = (__bf16)v;
                else
                    ((float*)Cv)[(size_t)row * N + col] = v;
            }
        }
    }
}

// ---------------------------------------------------------------------------
// FUSED conv+silu + x_dbl MFMA GEMM.
// Grid (BL/64, KSPLIT). Block tile: 64 rows x KC=256 channels.
// Phase 1: causal depthwise conv + silu on the tile -> xc16 (global) AND
//          Acv (LDS, ALDS-padded rows, 16B-aligned).
// Phase 2: K-loop over KC in 32-steps: B (WxT[128][DINNER]) staged via
//          global_load_lds (2-barrier, as verified in gemm_r64/xdbl_gemm);
//          A fragments read from resident Acv. fp32 partials out.
// ---------------------------------------------------------------------------
__global__ __launch_bounds__(256) void xdbl_fused2(
    const __bf16* __restrict__ xz16,   // [BL, NXZ], xb half
    const float* __restrict__ cwT,     // [4, DINNER]
    const float* __restrict__ cb,      // [DINNER]
    const __bf16* __restrict__ WxT,    // [96(pad128), DINNER] bf16
    __bf16* __restrict__ xc16,         // [BL, DINNER]
    float* __restrict__ parts)         // [KSPLIT, BL, XDP]
{
    __shared__ __bf16 Acv[64 * ALDS];  // 33 KB conv tile
    __shared__ __bf16 Bsm[128 * 32];   // 8 KB B k-slice

    const int tid  = threadIdx.x;
    const int w    = tid >> 6;
    const int lane = tid & 63;
    const int lrow = lane & 15;
    const int quad = lane >> 4;
    const int row0 = blockIdx.x * 64;
    const int kz   = blockIdx.y;
    const int kbeg = kz * KC;
    const int wc   = w * 32;

    // ---- Phase 1: conv tile -> Acv + xc16 (identical math to conv_prep) ----
    {
        const int ct = (tid & 31) * 8;
        const int rt = (tid >> 5) * 8;
        const int d  = kbeg + ct;

        float wreg[DCONV][8];
#pragma unroll
        for (int k = 0; k < DCONV; ++k) {
            float4 a = *(const float4*)(cwT + k * DINNER + d);
            float4 b = *(const float4*)(cwT + k * DINNER + d + 4);
            wreg[k][0]=a.x; wreg[k][1]=a.y; wreg[k][2]=a.z; wreg[k][3]=a.w;
            wreg[k][4]=b.x; wreg[k][5]=b.y; wreg[k][6]=b.z; wreg[k][7]=b.w;
        }
        float bias8[8];
        {
            float4 a = *(const float4*)(cb + d);
            float4 b = *(const float4*)(cb + d + 4);
            bias8[0]=a.x; bias8[1]=a.y; bias8[2]=a.z; bias8[3]=a.w;
            bias8[4]=b.x; bias8[5]=b.y; bias8[6]=b.z; bias8[7]=b.w;
        }

        const bf16x8 zero = {};
        bf16x8 win[DCONV];
        const int tloc0 = (int)((row0 + rt) & (SEQLEN - 1));
#pragma unroll
        for (int j = 0; j < DCONV - 1; ++j)
            win[j] = (tloc0 - 3 + j >= 0)
                ? *(const bf16x8*)(xz16 + (size_t)(row0 + rt - 3 + j) * NXZ + d)
                : zero;

        for (int i = 0; i < 8; ++i) {
            size_t r = (size_t)row0 + rt + i;
            win[DCONV - 1] = *(const bf16x8*)(xz16 + r * NXZ + d);
            bf16x8 o;
#pragma unroll
            for (int j = 0; j < 8; ++j) {
                float acc = bias8[j];
#pragma unroll
                for (int k = 0; k < DCONV; ++k)
                    acc += (float)win[k][j] * wreg[k][j];
                o[j] = (__bf16)silu_f(acc);
            }
            *(bf16x8*)(xc16 + r * DINNER + d) = o;
            *(bf16x8*)(Acv + (rt + i) * ALDS + ct) = o;
#pragma unroll
            for (int k = 0; k < DCONV - 1; ++k)
                win[k] = win[k + 1];
        }
    }
    __syncthreads();

    // ---- Phase 2: MFMA K-loop; B staged per 32-step, A from Acv ----
    const int ldr = tid >> 2;
    const int ldk = (tid & 3) * 8;
    const __bf16* gB = WxT + (size_t)ldr * DINNER + kbeg + ldk;
    const size_t half = (size_t)64 * DINNER;
    __bf16* lB0 = Bsm + w * 512;
    __bf16* lB1 = Bsm + 2048 + w * 512;

    floatx4 acc[4][2];
#pragma unroll
    for (int i = 0; i < 4; ++i)
#pragma unroll
        for (int j = 0; j < 2; ++j)
            acc[i][j] = (floatx4){0.f, 0.f, 0.f, 0.f};

    for (int k0 = 0; k0 < KC; k0 += 32) {
        gload_lds16(gB, lB0);
        gload_lds16(gB + half, lB1);
        gB += 32;
        __syncthreads();

        bf16x8 af[4], bf[2];
#pragma unroll
        for (int t = 0; t < 4; ++t)
            af[t] = *(const bf16x8*)(Acv + (t * 16 + lrow) * ALDS + k0 + quad * 8);
#pragma unroll
        for (int u = 0; u < 2; ++u)
            bf[u] = *(const bf16x8*)(Bsm + (wc + u * 16 + lrow) * 32 + quad * 8);

#pragma unroll
        for (int ti = 0; ti < 4; ++ti)
#pragma unroll
            for (int tj = 0; tj < 2; ++tj)
                acc[ti][tj] = __builtin_amdgcn_mfma_f32_16x16x32_bf16(
                    af[ti], bf[tj], acc[ti][tj], 0, 0, 0);
        __syncthreads();
    }

    const size_t base = (size_t)kz * BL * XDP;
#pragma unroll
    for (int ti = 0; ti < 4; ++ti) {
#pragma unroll
        for (int tj = 0; tj < 2; ++tj) {
            int col = wc + tj * 16 + lrow;
#pragma unroll
            for (int r = 0; r < 4; ++r) {
                int row = row0 + ti * 16 + quad * 4 + r;
                parts[base + (size_t)row * XDP + col] = acc[ti][tj][r];
            }
        }
    }
}

// Reduce KSPLIT partials (stride XDP=128, 96 valid cols) -> xdbl [BL,96] fp32
// + dtlow16 bf16 (cols < 64). float4-vectorized: 24 quads per row.
__global__ __launch_bounds__(256) void xdbl_reduce2(
    const float* __restrict__ parts, float* __restrict__ xdbl,
    __bf16* __restrict__ dtlow16)
{
    const int i4  = blockIdx.x * 256 + threadIdx.x;   // < BL*24
    const int row = i4 / 24;
    const int c4  = i4 - row * 24;
    const float* p = parts + (size_t)row * XDP + c4 * 4;
    floatx4 s = *(const floatx4*)p;
#pragma unroll
    for (int kz = 1; kz < KSPLIT; ++kz)
        s += *(const floatx4*)(p + (size_t)kz * BL * XDP);
    *(floatx4*)(xdbl + (size_t)row * XDBL_N + c4 * 4) = s;
    if (c4 < 16) {
        bf16x4 o = {(__bf16)s.x, (__bf16)s.y, (__bf16)s.z, (__bf16)s.w};
        *(bf16x4*)(dtlow16 + (size_t)row * DTRANK + c4 * 4) = o;
    }
}

// ---------------------------------------------------------------------------
// Merged preprocessing: x->bf16 cast, 4 transpose-casts, conv-w transpose.
// ---------------------------------------------------------------------------
#define NB_CAST  ((BL * DMODEL / 4) / 256)          // 4096
#define NB_WIN   ((NXZ / 32) * (DMODEL / 32))       // 4096
#define NB_WOUT  ((DMODEL / 32) * (DINNER / 32))    // 2048
#define NB_WDT   ((DINNER / 32) * (DTRANK / 32))    // 128
#define NB_CW    ((DCONV * DINNER) / 256)           // 32
#define NB_WXT   ((DINNER / 32) * (XDBL_N / 32))    // 192

__device__ __forceinline__ void transpose_tile(
    const float* __restrict__ src, __bf16* __restrict__ dst, int R, int Cc,
    int bx, int by, int tid, float* tile)
{
    int tx = tid & 31, ty = tid >> 5;   // 32 x 8
    int c0 = bx * 32, r0 = by * 32;
#pragma unroll
    for (int i = 0; i < 32; i += 8)
        tile[(ty + i) * 33 + tx] = src[(size_t)(r0 + ty + i) * Cc + c0 + tx];
    __syncthreads();
#pragma unroll
    for (int i = 0; i < 32; i += 8)
        dst[(size_t)(c0 + ty + i) * R + r0 + tx] = (__bf16)tile[tx * 33 + ty + i];
}

__global__ __launch_bounds__(256) void prep_kernel(
    const float* __restrict__ x,
    const float* __restrict__ W_in,
    const float* __restrict__ W_out,
    const float* __restrict__ W_dt,
    const float* __restrict__ W_x,
    const float* __restrict__ conv_w,
    __bf16* __restrict__ xb16,
    __bf16* __restrict__ WiT16,
    __bf16* __restrict__ WoT16,
    __bf16* __restrict__ WdtT16,
    __bf16* __restrict__ WxT16,
    float* __restrict__ cwT)
{
    __shared__ float tile[32 * 33];
    const int tid = threadIdx.x;
    int bid = blockIdx.x;

    if (bid < NB_CAST) {
        long i = ((long)bid * 256 + tid) * 4;
        float4 v = *(const float4*)(x + i);
        bf16x4 o = {(__bf16)v.x, (__bf16)v.y, (__bf16)v.z, (__bf16)v.w};
        *(bf16x4*)(xb16 + i) = o;
        return;
    }
    bid -= NB_CAST;
    if (bid < NB_WIN) {
        transpose_tile(W_in, WiT16, DMODEL, NXZ,
                       bid % (NXZ / 32), bid / (NXZ / 32), tid, tile);
        return;
    }
    bid -= NB_WIN;
    if (bid < NB_WOUT) {
        transpose_tile(W_out, WoT16, DINNER, DMODEL,
                       bid % (DMODEL / 32), bid / (DMODEL / 32), tid, tile);
        return;
    }
    bid -= NB_WOUT;
    if (bid < NB_WDT) {
        transpose_tile(W_dt, WdtT16, DTRANK, DINNER,
                       bid % (DINNER / 32), bid / (DINNER / 32), tid, tile);
        return;
    }
    bid -= NB_WDT;
    if (bid < NB_CW) {
        int i = bid * 256 + tid;                  // < DCONV*DINNER
        int k = i / DINNER, d = i % DINNER;
        cwT[i] = conv_w[d * DCONV + k];
        return;
    }
    bid -= NB_CW;
    {
        transpose_tile(W_x, WxT16, DINNER, XDBL_N,
                       bid % (XDBL_N / 32), bid / (XDBL_N / 32), tid, tile);
    }
}

// ---------------------------------------------------------------------------
// Chunked parallel scan (dt bf16, LCH=32, exp2-prescaled decay).
// B/C rows for the chunk are block-uniform -> staged once in LDS (broadcast
// ds_read_b128 per t instead of repeated global/scalar loads); t-loop
// unrolled x4 so dt/xc loads batch across iterations.
// NOTE: scan parallelism is at its empirical optimum here — both the R5
// state-split (more TLP) and R10 channel-pair (more ILP) variants regressed.
// ---------------------------------------------------------------------------
__global__ __launch_bounds__(256) void scan_pass1(
    const __bf16* __restrict__ dt16,
    const __bf16* __restrict__ xc16,
    const float* __restrict__ xdbl,
    const float* __restrict__ A_log,
    float* __restrict__ sums_h,
    float* __restrict__ sums_p)
{
    __shared__ __align__(16) float Bs[LCH][16];   // 2 KB: B rows of this chunk

    const int d  = blockIdx.x * 256 + threadIdx.x;
    const int bc = blockIdx.y;
    const int b  = bc / NCHUNK, c = bc % NCHUNK;
    const long r0 = (long)b * SEQLEN + (long)c * LCH;

    // stage B slice: 32 rows x 16 floats, 128 threads x 1 float4
    if (threadIdx.x < LCH * 4) {
        const int row = threadIdx.x >> 2, c4 = threadIdx.x & 3;
        *(float4*)&Bs[row][c4 * 4] =
            *(const float4*)(xdbl + (size_t)(r0 + row) * XDBL_N + DTRANK + c4 * 4);
    }

    float Ad[DSTATE];
    {
        const float4* al = (const float4*)(A_log + d * DSTATE);
#pragma unroll
        for (int q = 0; q < 4; ++q) {
            float4 v = al[q];
            Ad[q * 4 + 0] = -__expf(v.x) * 1.44269504f;
            Ad[q * 4 + 1] = -__expf(v.y) * 1.44269504f;
            Ad[q * 4 + 2] = -__expf(v.z) * 1.44269504f;
            Ad[q * 4 + 3] = -__expf(v.w) * 1.44269504f;
        }
    }
    __syncthreads();

    float h[DSTATE] = {};
    float Sdt = 0.f;

#pragma unroll 4
    for (int t = 0; t < LCH; ++t) {
        long r = r0 + t;
        float dtv = (float)dt16[r * DINNER + d];
        float xv  = (float)xc16[r * DINNER + d];
        float xdt = xv * dtv;
        Sdt += dtv;
        const float4* bv = (const float4*)Bs[t];
        float4 B0 = bv[0], B1 = bv[1], B2 = bv[2], B3 = bv[3];
        const float Bn[DSTATE] = {B0.x,B0.y,B0.z,B0.w, B1.x,B1.y,B1.z,B1.w,
                                  B2.x,B2.y,B2.z,B2.w, B3.x,B3.y,B3.z,B3.w};
#pragma unroll
        for (int n = 0; n < DSTATE; ++n) {
            float dA = fast_exp2(Ad[n] * dtv);
            h[n] = h[n] * dA + xdt * Bn[n];
        }
    }

    const long rowbase = (long)bc * DSTATE;
#pragma unroll
    for (int n = 0; n < DSTATE; ++n) {
        sums_h[(rowbase + n) * DINNER + d] = h[n];
        sums_p[(rowbase + n) * DINNER + d] = fast_exp2(Ad[n] * Sdt);
    }
}

__global__ __launch_bounds__(256) void scan_combine(
    float* __restrict__ sums_h, float* __restrict__ sums_p)
{
    int u = blockIdx.x * 256 + threadIdx.x;
    int d = u & (DINNER - 1);
    int n = (u >> 11) & (DSTATE - 1);
    int b = u >> 15;
    float hg = 0.f;
    for (int c = 0; c < NCHUNK; ++c) {
        long row = (long)(b * NCHUNK + c) * DSTATE + n;
        float p  = sums_p[row * DINNER + d];
        float hl = sums_h[row * DINNER + d];
        sums_p[row * DINNER + d] = hg;   // hstart for this chunk
        hg = p * hg + hl;
    }
}

// Pass 3: replay from hstart, fused gate, emit bf16 gated activation.
__global__ __launch_bounds__(256) void scan_pass3(
    const __bf16* __restrict__ dt16,
    const __bf16* __restrict__ xc16,
    const float* __restrict__ xdbl,
    const float* __restrict__ A_log,
    const __bf16* __restrict__ xz16,  // z half at col DINNER+d
    const float* __restrict__ sums_p, // hstart
    const float* __restrict__ Dp,
    __bf16* __restrict__ gated)       // [BL, DINNER] bf16
{
    __shared__ __align__(16) float BCs[LCH][32];  // 4 KB: B+C rows of chunk

    const int d  = blockIdx.x * 256 + threadIdx.x;
    const int bc = blockIdx.y;
    const int b  = bc / NCHUNK, c = bc % NCHUNK;
    const long r0 = (long)b * SEQLEN + (long)c * LCH;

    // stage B+C slice: 32 rows x 32 floats, 256 threads x 1 float4
    {
        const int row = threadIdx.x >> 3, c4 = threadIdx.x & 7;
        *(float4*)&BCs[row][c4 * 4] =
            *(const float4*)(xdbl + (size_t)(r0 + row) * XDBL_N + DTRANK + c4 * 4);
    }

    float Ad[DSTATE];
    {
        const float4* al = (const float4*)(A_log + d * DSTATE);
#pragma unroll
        for (int q = 0; q < 4; ++q) {
            float4 v = al[q];
            Ad[q * 4 + 0] = -__expf(v.x) * 1.44269504f;
            Ad[q * 4 + 1] = -__expf(v.y) * 1.44269504f;
            Ad[q * 4 + 2] = -__expf(v.z) * 1.44269504f;
            Ad[q * 4 + 3] = -__expf(v.w) * 1.44269504f;
        }
    }

    float h[DSTATE];
    const long rowbase = (long)bc * DSTATE;
#pragma unroll
    for (int n = 0; n < DSTATE; ++n)
        h[n] = sums_p[(rowbase + n) * DINNER + d];

    const float Dv = Dp[d];
    __syncthreads();

#pragma unroll 4
    for (int t = 0; t < LCH; ++t) {
        long r = r0 + t;
        float dtv = (float)dt16[r * DINNER + d];
        float xv  = (float)xc16[r * DINNER + d];
        float xdt = xv * dtv;
        const float4* bv = (const float4*)BCs[t];
        float4 B0 = bv[0], B1 = bv[1], B2 = bv[2], B3 = bv[3];
        float4 C0 = bv[4], C1 = bv[5], C2 = bv[6], C3 = bv[7];
        const float Bn[DSTATE] = {B0.x,B0.y,B0.z,B0.w, B1.x,B1.y,B1.z,B1.w,
                                  B2.x,B2.y,B2.z,B2.w, B3.x,B3.y,B3.z,B3.w};
        const float Cn[DSTATE] = {C0.x,C0.y,C0.z,C0.w, C1.x,C1.y,C1.z,C1.w,
                                  C2.x,C2.y,C2.z,C2.w, C3.x,C3.y,C3.z,C3.w};
        float y = 0.f;
#pragma unroll
        for (int n = 0; n < DSTATE; ++n) {
            float dA = fast_exp2(Ad[n] * dtv);
            h[n] = h[n] * dA + xdt * Bn[n];
            y += h[n] * Cn[n];
        }
        float z = (float)xz16[r * NXZ + DINNER + d];
        float yy = y + xv * Dv;
        gated[r * DINNER + d] = (__bf16)(yy * silu_f(z));
    }
}

// ---------------------------------------------------------------------------
extern "C" void kernel_launch(void* const* d_in, const int* in_sizes, int n_in,
                              void* d_out, int out_size, void* d_ws, size_t ws_size,
                              hipStream_t stream) {
    const float* x      = (const float*)d_in[0];
    const float* W_in   = (const float*)d_in[1];
    const float* conv_w = (const float*)d_in[2];
    const float* conv_b = (const float*)d_in[3];
    const float* W_x    = (const float*)d_in[4];
    const float* W_dt   = (const float*)d_in[5];
    const float* b_dt   = (const float*)d_in[6];
    const float* A_log  = (const float*)d_in[7];
    const float* Dp     = (const float*)d_in[8];
    const float* W_out  = (const float*)d_in[9];
    float* out = (float*)d_out;

    // Workspace layout (~141 MB):
    __bf16* xz16    = (__bf16*)d_ws;                    // BL*NXZ
    __bf16* xc16    = xz16 + (long)BL * NXZ;            // BL*DINNER
    __bf16* dt16    = xc16 + (long)BL * DINNER;         // BL*DINNER
    __bf16* gated16 = dt16 + (long)BL * DINNER;         // BL*DINNER
    __bf16* WoT16   = gated16 + (long)BL * DINNER;      // DINNER*DMODEL
    __bf16* WdtT16  = WoT16 + (long)DINNER * DMODEL;    // DINNER*DTRANK
    __bf16* dtlow16 = WdtT16 + (long)DINNER * DTRANK;   // BL*DTRANK
    __bf16* xb16    = dtlow16 + (long)BL * DTRANK;      // BL*DMODEL
    __bf16* WiT16   = xb16 + (long)BL * DMODEL;         // NXZ*DMODEL
    float*  xdbl    = (float*)(WiT16 + (long)NXZ * DMODEL);  // BL*96
    float*  cwT     = xdbl + (long)BL * XDBL_N;         // 4*DINNER
    float*  scratch = cwT + (long)DCONV * DINNER;       // partials, then sums
    float*  sums_h  = scratch;                          // 16.8 MB
    float*  sums_p  = scratch + (long)BATCH * NCHUNK * DSTATE * DINNER;
    // WxT16 [128][DINNER] bf16 (512 KB) lives at the sums_p base: written by
    // prep, read by xdbl_fused2 (whose partials occupy only the sums_h half
    // of scratch: KSPLIT*BL*XDP*4B = 16,777,216 B = sums_h size exactly);
    // sums_p is first written by scan_pass1, after WxT16 is dead.
    __bf16* WxT16 = (__bf16*)sums_p;
    // Out-GEMM split-K partials: overlay the xz16|xc16|dt16 region, which is
    // dead after scan_pass3. Size = KS_OUT*BL*DMODEL*4B = 67,108,864 B; the
    // region [0, gated16) is exactly (BL*NXZ + 2*BL*DINNER)*2B = 67,108,864 B.
    float* outparts = (float*)d_ws;

    dim3 blk(256);

    // 0) merged prep: cast + 4 weight transposes + conv-w transpose
    prep_kernel<<<dim3(NB_CAST + NB_WIN + NB_WOUT + NB_WDT + NB_CW + NB_WXT),
                  blk, 0, stream>>>(
        x, W_in, W_out, W_dt, W_x, conv_w, xb16, WiT16, WoT16, WdtT16, WxT16, cwT);

    // 1) xz = x @ W_in   (256x256 8-phase MFMA template, bf16 LDS-epilogue)
    gemm_bt_256<2><<<dim3((BL / 256) * (NXZ / 256)), dim3(512), 0, stream>>>(
        xb16, WiT16, xz16, BL, NXZ, DMODEL, DMODEL, nullptr);

    // 2+3) FUSED conv+silu (-> xc16) + x_dbl MFMA split-K partials, + reduce
    xdbl_fused2<<<dim3(BL / 64, KSPLIT), blk, 0, stream>>>(
        xz16, cwT, conv_b, WxT16, xc16, scratch);
    xdbl_reduce2<<<dim3((BL * 24) / 256), blk, 0, stream>>>(scratch, xdbl, dtlow16);

    // 4) dt = softplus(dt_low @ W_dt + b_dt)   (64-row tile, 1024 blocks)
    gemm_r64<3><<<dim3(DINNER / 128, BL / 64), blk, 0, stream>>>(
        dtlow16, WdtT16, dt16, BL, DINNER, DTRANK, b_dt);

    // 5) chunked scan: pass1 -> combine -> pass3 (+fused gate)
    {
        dim3 grid1(DINNER / 256, BATCH * NCHUNK);
        scan_pass1<<<grid1, blk, 0, stream>>>(dt16, xc16, xdbl, A_log, sums_h, sums_p);
        scan_combine<<<dim3((BATCH * DSTATE * DINNER) / 256), blk, 0, stream>>>(
            sums_h, sums_p);
        scan_pass3<<<grid1, blk, 0, stream>>>(dt16, xc16, xdbl, A_log, xz16,
                                              sums_p, Dp, gated16);
    }
    // 7) out = gated @ W_out: split-K x4 8-phase 256^2 partials (grid 64x4 =
    //    256 blocks = 1/CU, fp32 LDS-epilogue) + fp32 reduce.
    gemm_bt_256<0><<<dim3((BL / 256) * (DMODEL / 256), KS_OUT), dim3(512), 0, stream>>>(
        gated16, WoT16, outparts, BL, DMODEL, KCO, DINNER, nullptr);
    out_reduce<<<dim3((BL * DMODEL) / 1024), blk, 0, stream>>>(outparts, out);

    (void)in_sizes; (void)n_in; (void)out_size; (void)ws_size;
}